// Round 5
// baseline (106.951 us; speedup 1.0000x reference)
//
#include <hip/hip_runtime.h>
#include <hip/hip_bf16.h>

// u[b,o,y,x] = sum_d dist(p,d) * t[b,d,o],  t = v@W^T + bias
// GEMM: out[col*9216 + p] = sum_d D[p,d] * T2[col][d],  col = b*32+o
// D generated in registers. 32x32x16 MFMA. Block = 512 thr, 64 rows x 256
// cols; 8 waves = 4 col-groups x 2 k-groups (k-split inside BK=64 tile).
// K split 8 ways across blocks; kg pair merges via LDS; f16 partials.

typedef __bf16    bf16x8 __attribute__((ext_vector_type(8)));
typedef float     f32x4  __attribute__((ext_vector_type(4)));
typedef float     f32x16 __attribute__((ext_vector_type(16)));
typedef _Float16  f16x4  __attribute__((ext_vector_type(4)));

#define NPTS   9216      // 96*96
#define CIN    32
#define COUT   32
#define NCOLS  256       // 8 batches * 32 cout
#define SCALE  (1.0f / 95.0f)
#define OUTN   (NCOLS * NPTS)
#define NSPLIT 8
#define KCHUNK 1152      // NPTS / NSPLIT, divisible by 96
#define NTILES 18        // KCHUNK / 64

// ---------------- Kernel 1: projection  T2[col][d] = bf16(v . W^T + b) ----
__global__ __launch_bounds__(256) void proj_kernel(
    const float* __restrict__ v, const float* __restrict__ W,
    const float* __restrict__ bias, __bf16* __restrict__ T2)
{
    __shared__ float Wl[COUT * CIN];
    __shared__ float bl[COUT];
    const int t = threadIdx.x;
    for (int i = t; i < COUT * CIN; i += 256) Wl[i] = W[i];
    if (t < COUT) bl[t] = bias[t];
    __syncthreads();

    const int b = blockIdx.y;
    const int d = blockIdx.x * 256 + t;
    const float* vb = v + (size_t)b * CIN * NPTS + d;

    float acc[COUT];
#pragma unroll
    for (int o = 0; o < COUT; ++o) acc[o] = bl[o];
#pragma unroll 4
    for (int c = 0; c < CIN; ++c) {
        const float vv = vb[(size_t)c * NPTS];
#pragma unroll
        for (int o = 0; o < COUT; ++o) acc[o] += vv * Wl[o * CIN + c];
    }
#pragma unroll
    for (int o = 0; o < COUT; ++o)
        T2[(size_t)(b * COUT + o) * NPTS + d] = (__bf16)acc[o];
}

// ---------------- Kernel 2: implicit-D GEMM ------------------------------
__global__ __launch_bounds__(512, 4) void gemm_kernel(
    const __bf16* __restrict__ T2, void* __restrict__ dst, int usePartial)
{
    __shared__ __align__(1024) unsigned char lds[2][32768];

    const int tid  = threadIdx.x;
    const int wid  = tid >> 6;
    const int lane = tid & 63;
    const int l31  = lane & 31;
    const int hi   = lane >> 5;      // k-half within frag
    const int cg   = wid & 3;        // col group 0..3 (64 cols each)
    const int kg   = wid >> 2;       // k group: halves of each 64k tile

    const int bid  = blockIdx.x;
    const int z    = bid & 7;        // k-chunk id (XCD-aligned)
    const int x    = bid >> 3;       // row-block id, 0..143
    const int koff = z * KCHUNK;

    const int p0  = x * 64;
    const int prA = p0 + l31,  prB = prA + 32;   // m=0 / m=1 rows
    const int ypA = prA / 96, xpA = prA - ypA * 96;
    const int ypB = prB / 96, xpB = prB - ypB * 96;

    // d-coordinate tracker for this (kg, hi): d = tile*64 + kg*32 + s*16 + hi*8 + j
    int xi = kg * 32 + hi * 8;       // koff % 96 == 0
    int yi = z * 12;

    // staging: thread t loads col c0(+64i), 16B chunk (t&7)^(c0&7) of the
    // 128B k-row; LDS dest linear (tid*16) so the XOR swizzle lands right.
    const int c0 = tid >> 3;
    const int ch = (tid & 7) ^ (c0 & 7);
    const __bf16* gsrc = T2 + (size_t)c0 * NPTS + koff + ch * 8;
    const int ldst = tid * 16;

    auto stage = [&](int buf, int kt) {
#pragma unroll
        for (int i = 0; i < 4; ++i)
            __builtin_amdgcn_global_load_lds(
                (const __attribute__((address_space(1))) void*)
                    (gsrc + (size_t)kt * 64 + (size_t)i * 64 * NPTS),
                (__attribute__((address_space(3))) void*)
                    (&lds[buf][i * 8192 + ldst]),
                16, 0, 0);
    };

    f32x16 acc[2][2];
#pragma unroll
    for (int m = 0; m < 2; ++m)
#pragma unroll
        for (int n = 0; n < 2; ++n) acc[m][n] = (f32x16)(0.0f);

    stage(0, 0);
    __syncthreads();

    int cur = 0;
    for (int kt = 0; kt < NTILES; ++kt) {
        if (kt + 1 < NTILES) stage(cur ^ 1, kt + 1);

        const unsigned char* Lb = lds[cur];
        bf16x8 b[2][2];
#pragma unroll
        for (int s = 0; s < 2; ++s)
#pragma unroll
            for (int n = 0; n < 2; ++n) {
                const int col  = cg * 64 + n * 32 + l31;
                const int slot = (kg * 4 + s * 2 + hi) ^ (l31 & 7);
                b[s][n] = *(const bf16x8*)(Lb + col * 128 + slot * 16);
            }
#pragma unroll
        for (int s = 0; s < 2; ++s) {
            const int xr = xi + s * 16;
            const int xk = (xr >= 96) ? xr - 96 : xr;
            const int yk = (xr >= 96) ? yi + 1  : yi;
            const float dyA = (float)(ypA - yk) * SCALE;
            const float dyB = (float)(ypB - yk) * SCALE;
            const float dy2A = dyA * dyA, dy2B = dyB * dyB;
            float dxA = (float)(xpA - xk) * SCALE;
            float dxB = (float)(xpB - xk) * SCALE;
            bf16x8 aA, aB;
#pragma unroll
            for (int j = 0; j < 8; ++j) {
                aA[j] = (__bf16)__builtin_amdgcn_sqrtf(
                            __builtin_fmaf(dxA, dxA, dy2A));
                aB[j] = (__bf16)__builtin_amdgcn_sqrtf(
                            __builtin_fmaf(dxB, dxB, dy2B));
                dxA -= SCALE; dxB -= SCALE;
            }
            acc[0][0] = __builtin_amdgcn_mfma_f32_32x32x16_bf16(aA, b[s][0], acc[0][0], 0, 0, 0);
            acc[0][1] = __builtin_amdgcn_mfma_f32_32x32x16_bf16(aA, b[s][1], acc[0][1], 0, 0, 0);
            acc[1][0] = __builtin_amdgcn_mfma_f32_32x32x16_bf16(aB, b[s][0], acc[1][0], 0, 0, 0);
            acc[1][1] = __builtin_amdgcn_mfma_f32_32x32x16_bf16(aB, b[s][1], acc[1][1], 0, 0, 0);
        }
        xi += 64; if (xi >= 96) { xi -= 96; ++yi; }
        __syncthreads();
        cur ^= 1;
    }

    // -------- kg merge via LDS (both 32KB buffers free now) --------
    float* lf = (float*)lds;   // 16384 floats
    if (kg == 1) {
#pragma unroll
        for (int m = 0; m < 2; ++m)
#pragma unroll
            for (int n = 0; n < 2; ++n) {
                float* rg = lf + cg * 4096 + (m * 2 + n) * 1024;
#pragma unroll
                for (int q = 0; q < 4; ++q) {
                    f32x4 vv = { acc[m][n][4*q], acc[m][n][4*q+1],
                                 acc[m][n][4*q+2], acc[m][n][4*q+3] };
                    *(f32x4*)(rg + q * 256 + lane * 4) = vv;
                }
            }
    }
    __syncthreads();
    if (kg == 0) {
        // C/D layout (32x32): col=lane&31, row = 8q + 4*hi + r
        if (usePartial) {
            _Float16* pb = (_Float16*)dst + (size_t)z * OUTN;
#pragma unroll
            for (int m = 0; m < 2; ++m)
#pragma unroll
                for (int n = 0; n < 2; ++n) {
                    const int col = cg * 64 + n * 32 + l31;
                    float* rg = lf + cg * 4096 + (m * 2 + n) * 1024;
                    _Float16* ob = pb + (size_t)col * NPTS + p0 + m * 32 + 4 * hi;
#pragma unroll
                    for (int q = 0; q < 4; ++q) {
                        f32x4 o = *(f32x4*)(rg + q * 256 + lane * 4);
                        f16x4 h = { (_Float16)(acc[m][n][4*q]   + o[0]),
                                    (_Float16)(acc[m][n][4*q+1] + o[1]),
                                    (_Float16)(acc[m][n][4*q+2] + o[2]),
                                    (_Float16)(acc[m][n][4*q+3] + o[3]) };
                        *(f16x4*)(ob + q * 8) = h;
                    }
                }
        } else {
            float* ob0 = (float*)dst;
#pragma unroll
            for (int m = 0; m < 2; ++m)
#pragma unroll
                for (int n = 0; n < 2; ++n) {
                    const int col = cg * 64 + n * 32 + l31;
                    float* rg = lf + cg * 4096 + (m * 2 + n) * 1024;
                    float* ob = ob0 + (size_t)col * NPTS + p0 + m * 32 + 4 * hi;
#pragma unroll
                    for (int q = 0; q < 4; ++q) {
                        f32x4 o = *(f32x4*)(rg + q * 256 + lane * 4);
#pragma unroll
                        for (int r = 0; r < 4; ++r)
                            atomicAdd(ob + q * 8 + r, acc[m][n][4*q+r] + o[r]);
                    }
                }
        }
    }
}

// ---------------- Kernel 3: reduce NSPLIT f16 partials --------------------
__global__ __launch_bounds__(256) void reduce_kernel(
    const _Float16* __restrict__ part, float* __restrict__ out)
{
    const size_t i = ((size_t)blockIdx.x * 256 + threadIdx.x) * 4;
    f32x4 a = { 0.f, 0.f, 0.f, 0.f };
#pragma unroll
    for (int s = 0; s < NSPLIT; ++s) {
        f16x4 v = *(const f16x4*)(part + (size_t)s * OUTN + i);
        a[0] += (float)v[0]; a[1] += (float)v[1];
        a[2] += (float)v[2]; a[3] += (float)v[3];
    }
    *(f32x4*)(out + i) = a;
}

extern "C" void kernel_launch(void* const* d_in, const int* in_sizes, int n_in,
                              void* d_out, int out_size, void* d_ws, size_t ws_size,
                              hipStream_t stream) {
    const float* v    = (const float*)d_in[0];  // (8,32,96,96)
    const float* W    = (const float*)d_in[1];  // (32,32)
    const float* bias = (const float*)d_in[2];  // (32,)
    float* out = (float*)d_out;                 // (8,32,96,96) f32
    __bf16* T2 = (__bf16*)d_ws;                 // 256 x 9216 bf16 = 4.72 MB

    const size_t t2b = (size_t)NCOLS * NPTS * 2;
    const int usePartial = (ws_size >= t2b + (size_t)NSPLIT * OUTN * 2) ? 1 : 0;
    _Float16* partial = (_Float16*)((char*)d_ws + t2b);

    proj_kernel<<<dim3(36, 8), 256, 0, stream>>>(v, W, bias, T2);
    if (usePartial) {
        gemm_kernel<<<144 * NSPLIT, 512, 0, stream>>>(T2, partial, 1);
        reduce_kernel<<<OUTN / 1024, 256, 0, stream>>>(partial, out);
    } else {
        hipMemsetAsync(d_out, 0, (size_t)out_size * sizeof(float), stream);
        gemm_kernel<<<144 * NSPLIT, 512, 0, stream>>>(T2, out, 0);
    }
}

// Round 6
// 101.605 us; speedup vs baseline: 1.0526x; 1.0526x over previous
//
#include <hip/hip_runtime.h>
#include <hip/hip_bf16.h>

// u[b,o,y,x] = sum_d dist(p,d) * t[b,d,o],  t = v@W^T + bias
// GEMM: out[col*9216 + p] = sum_d D[p,d] * T2[col][d],  col = b*32+o
// D generated in registers (fma+sqrt+perm-pack, ~3.5 VALU + 1 trans / elem).
// 32x32x16 MFMA. Block = 256 thr = 4 waves (2 row-grp x 2 col-grp),
// wave = 64 rows x 128 cols (acc 2x4). Block tile 128r x 256c, BK=64.
// K split 8 ways across blocks; f16 partials + reduce kernel.

typedef __bf16    bf16x8 __attribute__((ext_vector_type(8)));
typedef float     f32x4  __attribute__((ext_vector_type(4)));
typedef float     f32x16 __attribute__((ext_vector_type(16)));
typedef _Float16  f16x4  __attribute__((ext_vector_type(4)));
typedef _Float16  f16x8  __attribute__((ext_vector_type(8)));

#define NPTS   9216      // 96*96
#define CIN    32
#define COUT   32
#define NCOLS  256       // 8 batches * 32 cout
#define SCALE  (1.0f / 95.0f)
#define OUTN   (NCOLS * NPTS)
#define NSPLIT 8
#define KCHUNK 1152      // NPTS / NSPLIT, divisible by 96
#define NTILES 18        // KCHUNK / 64

// ---------------- Kernel 1: projection  T2[col][d] = bf16(v . W^T + b) ----
__global__ __launch_bounds__(256) void proj_kernel(
    const float* __restrict__ v, const float* __restrict__ W,
    const float* __restrict__ bias, __bf16* __restrict__ T2)
{
    __shared__ float Wl[COUT * CIN];
    __shared__ float bl[COUT];
    const int t = threadIdx.x;
    for (int i = t; i < COUT * CIN; i += 256) Wl[i] = W[i];
    if (t < COUT) bl[t] = bias[t];
    __syncthreads();

    const int b = blockIdx.y;
    const int d = blockIdx.x * 256 + t;
    const float* vb = v + (size_t)b * CIN * NPTS + d;

    float acc[COUT];
#pragma unroll
    for (int o = 0; o < COUT; ++o) acc[o] = bl[o];
#pragma unroll 4
    for (int c = 0; c < CIN; ++c) {
        const float vv = vb[(size_t)c * NPTS];
#pragma unroll
        for (int o = 0; o < COUT; ++o) acc[o] += vv * Wl[o * CIN + c];
    }
#pragma unroll
    for (int o = 0; o < COUT; ++o)
        T2[(size_t)(b * COUT + o) * NPTS + d] = (__bf16)acc[o];
}

// ---------------- A-fragment generator -----------------------------------
// dist values packed to bf16 via round-half-up + v_perm (1.5 VALU / 2 elem).
__device__ __forceinline__ bf16x8 agen(float dx, float dy2) {
    float f[8];
#pragma unroll
    for (int j = 0; j < 8; ++j) {
        f[j] = __builtin_amdgcn_sqrtf(__builtin_fmaf(dx, dx, dy2));
        dx -= SCALE;
    }
    union { unsigned int u[4]; bf16x8 v; } pk;
#pragma unroll
    for (int q = 0; q < 4; ++q) {
        const unsigned int lo = __builtin_bit_cast(unsigned int, f[2*q])   + 0x8000u;
        const unsigned int hi = __builtin_bit_cast(unsigned int, f[2*q+1]) + 0x8000u;
        pk.u[q] = __builtin_amdgcn_perm(hi, lo, 0x07060302u);  // [hi16(hi)|hi16(lo)]
    }
    return pk.v;
}

// ---------------- Kernel 2: implicit-D GEMM ------------------------------
__global__ __launch_bounds__(256, 2) void gemm_kernel(
    const __bf16* __restrict__ T2, void* __restrict__ dst, int usePartial)
{
    __shared__ __align__(1024) unsigned char lds[2][32768];

    const int tid  = threadIdx.x;
    const int wid  = tid >> 6;
    const int lane = tid & 63;
    const int l31  = lane & 31;
    const int hi   = lane >> 5;      // k-half within frag
    const int rg   = wid >> 1;       // row group 0..1 (64 rows each)
    const int cg   = wid & 1;        // col group 0..1 (128 cols each)

    const int bid  = blockIdx.x;
    const int z    = bid & 7;        // k-chunk id
    const int x    = bid >> 3;       // row-block id, 0..71
    const int koff = z * KCHUNK;

    const int pbase = x * 128 + rg * 64;
    const int prA = pbase + l31,  prB = prA + 32;     // m=0 / m=1 rows
    const int ypA = prA / 96, xpA = prA - ypA * 96;
    const int ypB = prB / 96, xpB = prB - ypB * 96;
    const int xphA = xpA - hi * 8;   // hi fold pre-applied
    const int xphB = xpB - hi * 8;

    // staging: thread t loads col c0(+32i), 16B chunk (t&7)^(c0&7) of the
    // 128B k-row; global_load_lds dest is wave-base + lane*16 (linear).
    const int c0 = tid >> 3;
    const int ch = (tid & 7) ^ (c0 & 7);
    const __bf16* gsrc = T2 + (size_t)c0 * NPTS + koff + ch * 8;
    const int ldst = tid * 16;

    auto stage = [&](int buf, int kt) {
#pragma unroll
        for (int i = 0; i < 8; ++i)
            __builtin_amdgcn_global_load_lds(
                (const __attribute__((address_space(1))) void*)
                    (gsrc + (size_t)kt * 64 + (size_t)i * 32 * NPTS),
                (__attribute__((address_space(3))) void*)
                    (&lds[buf][i * 4096 + ldst]),
                16, 0, 0);
    };

    f32x16 acc[2][4];
#pragma unroll
    for (int m = 0; m < 2; ++m)
#pragma unroll
        for (int n = 0; n < 4; ++n) acc[m][n] = (f32x16)(0.0f);

    stage(0, 0);
    __syncthreads();

    int xt = 0, yt = z * 12;         // k-tile base coords (koff % 96 == 0)
    int cur = 0;
    for (int kt = 0; kt < NTILES; ++kt) {
        if (kt + 1 < NTILES) stage(cur ^ 1, kt + 1);
        const unsigned char* Lb = lds[cur];

#pragma unroll
        for (int s = 0; s < 4; ++s) {       // 4 k-steps of 16
            const int xr = xt + s * 16;     // never straddles 96 within 8
            const int xk = (xr >= 96) ? xr - 96 : xr;
            const int yk = (xr >= 96) ? yt + 1  : yt;
            const float dyA = (float)(ypA - yk) * SCALE;
            const float dyB = (float)(ypB - yk) * SCALE;
            const bf16x8 aA = agen((float)(xphA - xk) * SCALE, dyA * dyA);
            const bf16x8 aB = agen((float)(xphB - xk) * SCALE, dyB * dyB);
#pragma unroll
            for (int n = 0; n < 4; ++n) {
                const int col  = cg * 128 + n * 32 + l31;
                const int slot = (s * 2 + hi) ^ (l31 & 7);
                const bf16x8 b = *(const bf16x8*)(Lb + col * 128 + slot * 16);
                acc[0][n] = __builtin_amdgcn_mfma_f32_32x32x16_bf16(
                    aA, b, acc[0][n], 0, 0, 0);
                acc[1][n] = __builtin_amdgcn_mfma_f32_32x32x16_bf16(
                    aB, b, acc[1][n], 0, 0, 0);
            }
        }
        xt += 64; if (xt >= 96) { xt -= 96; ++yt; }
        __syncthreads();
        cur ^= 1;
    }

    // epilogue: 32x32 C/D: col=lane&31, row=(r&3)+8*(r>>2)+4*hi
    if (usePartial) {
        _Float16* pb = (_Float16*)dst + (size_t)z * OUTN;
#pragma unroll
        for (int m = 0; m < 2; ++m)
#pragma unroll
            for (int n = 0; n < 4; ++n) {
                const int col = cg * 128 + n * 32 + l31;
                _Float16* ob = pb + (size_t)col * NPTS + pbase + m * 32 + 4 * hi;
#pragma unroll
                for (int q = 0; q < 4; ++q) {
                    f16x4 h = { (_Float16)acc[m][n][4*q],
                                (_Float16)acc[m][n][4*q+1],
                                (_Float16)acc[m][n][4*q+2],
                                (_Float16)acc[m][n][4*q+3] };
                    *(f16x4*)(ob + q * 8) = h;
                }
            }
    } else {
        float* ob0 = (float*)dst;
#pragma unroll
        for (int m = 0; m < 2; ++m)
#pragma unroll
            for (int n = 0; n < 4; ++n) {
                const int col = cg * 128 + n * 32 + l31;
                float* ob = ob0 + (size_t)col * NPTS + pbase + m * 32 + 4 * hi;
#pragma unroll
                for (int q = 0; q < 4; ++q)
#pragma unroll
                    for (int r = 0; r < 4; ++r)
                        atomicAdd(ob + q * 8 + r, acc[m][n][4*q+r]);
            }
    }
}

// ---------------- Kernel 3: reduce NSPLIT f16 partials --------------------
__global__ __launch_bounds__(256) void reduce_kernel(
    const _Float16* __restrict__ part, float* __restrict__ out)
{
    const size_t i = ((size_t)blockIdx.x * 256 + threadIdx.x) * 8;
    float a[8] = {};
#pragma unroll
    for (int s = 0; s < NSPLIT; ++s) {
        f16x8 v = *(const f16x8*)(part + (size_t)s * OUTN + i);
#pragma unroll
        for (int r = 0; r < 8; ++r) a[r] += (float)v[r];
    }
    f32x4 o0 = { a[0], a[1], a[2], a[3] };
    f32x4 o1 = { a[4], a[5], a[6], a[7] };
    *(f32x4*)(out + i)     = o0;
    *(f32x4*)(out + i + 4) = o1;
}

extern "C" void kernel_launch(void* const* d_in, const int* in_sizes, int n_in,
                              void* d_out, int out_size, void* d_ws, size_t ws_size,
                              hipStream_t stream) {
    const float* v    = (const float*)d_in[0];  // (8,32,96,96)
    const float* W    = (const float*)d_in[1];  // (32,32)
    const float* bias = (const float*)d_in[2];  // (32,)
    float* out = (float*)d_out;                 // (8,32,96,96) f32
    __bf16* T2 = (__bf16*)d_ws;                 // 256 x 9216 bf16 = 4.72 MB

    const size_t t2b = (size_t)NCOLS * NPTS * 2;
    const int usePartial = (ws_size >= t2b + (size_t)NSPLIT * OUTN * 2) ? 1 : 0;
    _Float16* partial = (_Float16*)((char*)d_ws + t2b);

    proj_kernel<<<dim3(36, 8), 256, 0, stream>>>(v, W, bias, T2);
    if (usePartial) {
        gemm_kernel<<<72 * NSPLIT, 256, 0, stream>>>(T2, partial, 1);
        reduce_kernel<<<OUTN / 2048, 256, 0, stream>>>(partial, out);
    } else {
        hipMemsetAsync(d_out, 0, (size_t)out_size * sizeof(float), stream);
        gemm_kernel<<<72 * NSPLIT, 256, 0, stream>>>(T2, out, 0);
    }
}

// Round 7
// 89.362 us; speedup vs baseline: 1.1968x; 1.1370x over previous
//
#include <hip/hip_runtime.h>
#include <hip/hip_bf16.h>

// u[b,o,y,x] = sum_d dist(p,d) * t[b,d,o],  t = v@W^T + bias
// GEMM: out[col*9216 + p] = sum_d D[p,d] * T2[col][d],  col = b*32+o
// D generated in registers (fma+sqrt+perm-pack). 32x32x16 MFMA.
// Block = 256 thr = 4 waves, wave = 32 rows x 128 cols (acc 1x4 -> 64 VGPR).
// Block tile 128r x 128c, BK=64 double-buffered (32KB LDS) -> 4 blocks/CU.
// K split 12 ways, grid 72x2x12 = 1728; f16 partials + reduce kernel.

typedef __bf16    bf16x8 __attribute__((ext_vector_type(8)));
typedef float     f32x4  __attribute__((ext_vector_type(4)));
typedef float     f32x16 __attribute__((ext_vector_type(16)));
typedef _Float16  f16x4  __attribute__((ext_vector_type(4)));
typedef _Float16  f16x8  __attribute__((ext_vector_type(8)));

#define NPTS   9216      // 96*96
#define CIN    32
#define COUT   32
#define NCOLS  256       // 8 batches * 32 cout
#define SCALE  (1.0f / 95.0f)
#define OUTN   (NCOLS * NPTS)
#define NSPLIT 12
#define KCHUNK 768       // NPTS / NSPLIT, = 8*96 (koff%96==0)
#define NTILES 12        // KCHUNK / 64

// ---------------- Kernel 1: projection  T2[col][d] = bf16(v . W^T + b) ----
__global__ __launch_bounds__(256) void proj_kernel(
    const float* __restrict__ v, const float* __restrict__ W,
    const float* __restrict__ bias, __bf16* __restrict__ T2)
{
    __shared__ float Wl[COUT * CIN];
    __shared__ float bl[COUT];
    const int t = threadIdx.x;
    for (int i = t; i < COUT * CIN; i += 256) Wl[i] = W[i];
    if (t < COUT) bl[t] = bias[t];
    __syncthreads();

    const int b = blockIdx.y;
    const int d = blockIdx.x * 256 + t;
    const float* vb = v + (size_t)b * CIN * NPTS + d;

    float acc[COUT];
#pragma unroll
    for (int o = 0; o < COUT; ++o) acc[o] = bl[o];
#pragma unroll 4
    for (int c = 0; c < CIN; ++c) {
        const float vv = vb[(size_t)c * NPTS];
#pragma unroll
        for (int o = 0; o < COUT; ++o) acc[o] += vv * Wl[o * CIN + c];
    }
#pragma unroll
    for (int o = 0; o < COUT; ++o)
        T2[(size_t)(b * COUT + o) * NPTS + d] = (__bf16)acc[o];
}

// ---------------- A-fragment generator -----------------------------------
// dist values packed to bf16 via round-half-up + v_perm.
__device__ __forceinline__ bf16x8 agen(float dx, float dy2) {
    float f[8];
#pragma unroll
    for (int j = 0; j < 8; ++j) {
        f[j] = __builtin_amdgcn_sqrtf(__builtin_fmaf(dx, dx, dy2));
        dx -= SCALE;
    }
    union { unsigned int u[4]; bf16x8 v; } pk;
#pragma unroll
    for (int q = 0; q < 4; ++q) {
        const unsigned int lo = __builtin_bit_cast(unsigned int, f[2*q])   + 0x8000u;
        const unsigned int hi = __builtin_bit_cast(unsigned int, f[2*q+1]) + 0x8000u;
        pk.u[q] = __builtin_amdgcn_perm(hi, lo, 0x07060302u);  // [hi16(hi)|hi16(lo)]
    }
    return pk.v;
}

// ---------------- Kernel 2: implicit-D GEMM ------------------------------
__global__ __launch_bounds__(256, 4) void gemm_kernel(
    const __bf16* __restrict__ T2, void* __restrict__ dst, int usePartial)
{
    __shared__ __align__(1024) unsigned char lds[2][16384];

    const int tid  = threadIdx.x;
    const int wid  = tid >> 6;
    const int lane = tid & 63;
    const int l31  = lane & 31;
    const int hi   = lane >> 5;      // k-half within frag

    const int bid = blockIdx.x;
    const int z   = bid % NSPLIT;    // k-chunk id
    const int rem = bid / NSPLIT;
    const int cb  = rem & 1;         // col-block 0..1
    const int x   = rem >> 1;        // row-block 0..71
    const int koff = z * KCHUNK;
    const int colBase = cb * 128;

    const int prow = x * 128 + wid * 32 + l31;   // this lane's A row
    const int yp = prow / 96, xp = prow - yp * 96;
    const int xph = xp - hi * 8;     // hi fold pre-applied

    // staging: 4 x global_load_lds(16B); dest = buf + i*4096 + tid*16
    // (lane-stride 16 = legal). LDS layout: [col][8 chunks of 16B],
    // physical chunk = logical ^ (col&7); source pre-swizzled to match.
    const int scol = tid >> 3;               // col 0..31 (+32*i)
    const int sch  = (tid & 7) ^ (scol & 7);
    const __bf16* gsrc = T2 + (size_t)(colBase + scol) * NPTS + koff + sch * 8;
    const int ldst = tid * 16;

    auto stage = [&](int buf, int kt) {
#pragma unroll
        for (int i = 0; i < 4; ++i)
            __builtin_amdgcn_global_load_lds(
                (const __attribute__((address_space(1))) void*)
                    (gsrc + (size_t)kt * 64 + (size_t)i * 32 * NPTS),
                (__attribute__((address_space(3))) void*)
                    (&lds[buf][i * 4096 + ldst]),
                16, 0, 0);
    };

    f32x16 acc[4];
#pragma unroll
    for (int n = 0; n < 4; ++n) acc[n] = (f32x16)(0.0f);

    stage(0, 0);
    __syncthreads();

    int xt = 0, yt = z * 8;          // k-tile base coords (koff%96 == 0)
    int cur = 0;
    for (int kt = 0; kt < NTILES; ++kt) {
        if (kt + 1 < NTILES) stage(cur ^ 1, kt + 1);
        const unsigned char* Lb = lds[cur];

#pragma unroll
        for (int s = 0; s < 4; ++s) {        // 4 k-steps of 16
            const int xr = xt + s * 16;
            const int xk = (xr >= 96) ? xr - 96 : xr;
            const int yk = (xr >= 96) ? yt + 1  : yt;
            const float dy = (float)(yp - yk) * SCALE;
            const bf16x8 a = agen((float)(xph - xk) * SCALE, dy * dy);
#pragma unroll
            for (int n = 0; n < 4; ++n) {
                const int col  = n * 32 + l31;
                const int slot = (s * 2 + hi) ^ (col & 7);
                const bf16x8 b = *(const bf16x8*)(Lb + col * 128 + slot * 16);
                acc[n] = __builtin_amdgcn_mfma_f32_32x32x16_bf16(
                    a, b, acc[n], 0, 0, 0);
            }
        }
        xt += 64; if (xt >= 96) { xt -= 96; ++yt; }
        __syncthreads();
        cur ^= 1;
    }

    // epilogue: 32x32 C/D: col=lane&31, row=(r&3)+8*(r>>2)+4*hi
    const int rowb = x * 128 + wid * 32;
    if (usePartial) {
        _Float16* pb = (_Float16*)dst + (size_t)z * OUTN;
#pragma unroll
        for (int n = 0; n < 4; ++n) {
            const int col = colBase + n * 32 + l31;
            _Float16* ob = pb + (size_t)col * NPTS + rowb + 4 * hi;
#pragma unroll
            for (int q = 0; q < 4; ++q) {
                f16x4 h = { (_Float16)acc[n][4*q],
                            (_Float16)acc[n][4*q+1],
                            (_Float16)acc[n][4*q+2],
                            (_Float16)acc[n][4*q+3] };
                *(f16x4*)(ob + q * 8) = h;
            }
        }
    } else {
        float* ob0 = (float*)dst;
#pragma unroll
        for (int n = 0; n < 4; ++n) {
            const int col = colBase + n * 32 + l31;
            float* ob = ob0 + (size_t)col * NPTS + rowb + 4 * hi;
#pragma unroll
            for (int q = 0; q < 4; ++q)
#pragma unroll
                for (int r = 0; r < 4; ++r)
                    atomicAdd(ob + q * 8 + r, acc[n][4*q+r]);
        }
    }
}

// ---------------- Kernel 3: reduce NSPLIT f16 partials --------------------
__global__ __launch_bounds__(256) void reduce_kernel(
    const _Float16* __restrict__ part, float* __restrict__ out)
{
    const size_t i = ((size_t)blockIdx.x * 256 + threadIdx.x) * 8;
    float a[8] = {};
#pragma unroll
    for (int s = 0; s < NSPLIT; ++s) {
        f16x8 v = *(const f16x8*)(part + (size_t)s * OUTN + i);
#pragma unroll
        for (int r = 0; r < 8; ++r) a[r] += (float)v[r];
    }
    f32x4 o0 = { a[0], a[1], a[2], a[3] };
    f32x4 o1 = { a[4], a[5], a[6], a[7] };
    *(f32x4*)(out + i)     = o0;
    *(f32x4*)(out + i + 4) = o1;
}

extern "C" void kernel_launch(void* const* d_in, const int* in_sizes, int n_in,
                              void* d_out, int out_size, void* d_ws, size_t ws_size,
                              hipStream_t stream) {
    const float* v    = (const float*)d_in[0];  // (8,32,96,96)
    const float* W    = (const float*)d_in[1];  // (32,32)
    const float* bias = (const float*)d_in[2];  // (32,)
    float* out = (float*)d_out;                 // (8,32,96,96) f32
    __bf16* T2 = (__bf16*)d_ws;                 // 256 x 9216 bf16 = 4.72 MB

    const size_t t2b = (size_t)NCOLS * NPTS * 2;
    const int usePartial = (ws_size >= t2b + (size_t)NSPLIT * OUTN * 2) ? 1 : 0;
    _Float16* partial = (_Float16*)((char*)d_ws + t2b);

    proj_kernel<<<dim3(36, 8), 256, 0, stream>>>(v, W, bias, T2);
    if (usePartial) {
        gemm_kernel<<<72 * 2 * NSPLIT, 256, 0, stream>>>(T2, partial, 1);
        reduce_kernel<<<OUTN / 2048, 256, 0, stream>>>(partial, out);
    } else {
        hipMemsetAsync(d_out, 0, (size_t)out_size * sizeof(float), stream);
        gemm_kernel<<<72 * 2 * NSPLIT, 256, 0, stream>>>(T2, out, 0);
    }
}